// Round 1
// baseline (1671.582 us; speedup 1.0000x reference)
//
#include <hip/hip_runtime.h>
#include <hip/hip_bf16.h>
#include <math.h>

#define IGNORE_INDEX (-100)

constexpr int N = 8192;
constexpr int D = 1024;
constexpr int V = 50257;

constexpr int BM = 128;
constexpr int BN = 128;
constexpr int BK = 64;
constexpr int NC = 16;                   // V-chunks (grid.x)
constexpr int SUBT = (V + BN - 1) / BN;  // 393 column subtiles

typedef __attribute__((ext_vector_type(8))) short short8;
typedef __attribute__((ext_vector_type(4))) float floatx4;

__device__ __forceinline__ void gload_lds16(const void* g, void* l) {
  __builtin_amdgcn_global_load_lds(
      (const __attribute__((address_space(1))) void*)g,
      (__attribute__((address_space(3))) void*)l, 16, 0, 0);
}

// ---------------- fp32 -> bf16 cast (RNE) ----------------
__device__ __forceinline__ unsigned short f2bf(float f) {
  unsigned u = __float_as_uint(f);
  u += 0x7fffu + ((u >> 16) & 1u);
  return (unsigned short)(u >> 16);
}

__global__ void cast_bf16_kernel(const float* __restrict__ in,
                                 unsigned short* __restrict__ out, int n4) {
  int idx = blockIdx.x * blockDim.x + threadIdx.x;
  if (idx >= n4) return;
  const float4 v = ((const float4*)in)[idx];
  ushort4 o;
  o.x = f2bf(v.x); o.y = f2bf(v.y); o.z = f2bf(v.z); o.w = f2bf(v.w);
  ((ushort4*)out)[idx] = o;
}

// ---------------- exact fp32 target-logit dot ----------------
__global__ void tgt_dot_kernel(const float* __restrict__ e,
                               const float* __restrict__ c,
                               const int* __restrict__ t,
                               float* __restrict__ tgt) {
  const int row = blockIdx.x * 4 + (threadIdx.x >> 6);
  const int lane = threadIdx.x & 63;
  int tr = t[row];
  if (tr == IGNORE_INDEX) tr = 0;
  const float4* ev = (const float4*)(e + (size_t)row * D);
  const float4* cv = (const float4*)(c + (size_t)tr * D);
  float s = 0.f;
#pragma unroll
  for (int k = 0; k < 4; ++k) {
    float4 a = ev[lane + k * 64];
    float4 b = cv[lane + k * 64];
    s += a.x * b.x + a.y * b.y + a.z * b.z + a.w * b.w;
  }
#pragma unroll
  for (int d = 1; d < 64; d <<= 1) s += __shfl_xor(s, d, 64);
  if (lane == 0) tgt[row] = s;
}

// ---------------- fused bf16 GEMM + online logsumexp partials ----------------
// A = e_bf16 [N][D], B = c_bf16 [V][D] (both K-major: exactly MFMA A/B frag order)
__global__ __launch_bounds__(256) void gemm_lse_kernel(
    const unsigned short* __restrict__ A, const unsigned short* __restrict__ B,
    float* __restrict__ m_part, float* __restrict__ s_part) {
  __shared__ char smA[BM * BK * 2];  // 16 KB, rows of 8 x 16B vecs, XOR-swizzled
  __shared__ char smB[BN * BK * 2];  // 16 KB
  __shared__ float red_m[2][BM];
  __shared__ float red_s[2][BM];

  const int chunk = blockIdx.x;
  const int row0 = blockIdx.y * BM;
  const int tid = threadIdx.x;
  const int wave = tid >> 6;
  const int lane = tid & 63;
  const int wr = wave >> 1;  // wave row 0..1  (64-row half)
  const int wc = wave & 1;   // wave col 0..1  (64-col half)
  const int quad = lane >> 4;
  const int l16 = lane & 15;

  // staging geometry: each wave fills 4 x 1KB LDS chunks for A and B.
  // lane's LDS slot is fixed (base + lane*16); we pick the global source so
  // that physical vec pv holds logical vec lv = pv ^ (row&7)  (XOR swizzle).
  const int lrow = lane >> 3;             // row within 8-row chunk
  const int lvec_st = (lane & 7) ^ lrow;  // swizzled source 16B-vector index

  float run_m = -INFINITY, run_s = 0.0f;  // meaningful for tid < 128

  const int nsub = (SUBT - chunk + NC - 1) / NC;  // round-robin subtiles
  for (int si = 0; si < nsub; ++si) {
    const int col0 = (chunk + si * NC) * BN;
    floatx4 acc[4][4];
#pragma unroll
    for (int i = 0; i < 4; ++i)
#pragma unroll
      for (int j = 0; j < 4; ++j) acc[i][j] = floatx4{0.f, 0.f, 0.f, 0.f};

    for (int ks = 0; ks < D / BK; ++ks) {
      const int k0 = ks * BK;
      __syncthreads();  // previous ds_reads done before overwrite
#pragma unroll
      for (int cc = 0; cc < 4; ++cc) {
        const int ch = wave * 4 + cc;
        const int arow = row0 + ch * 8 + lrow;
        gload_lds16((const char*)(A + (size_t)arow * D + k0) + lvec_st * 16,
                    smA + ch * 1024 + lane * 16);
        int brow = col0 + ch * 8 + lrow;
        if (brow >= V) brow = V - 1;  // dup last row; masked in stats
        gload_lds16((const char*)(B + (size_t)brow * D + k0) + lvec_st * 16,
                    smB + ch * 1024 + lane * 16);
      }
      __syncthreads();  // compiler drains vmcnt(0) before barrier
#pragma unroll
      for (int kk = 0; kk < 2; ++kk) {
        short8 af[4], bf[4];
#pragma unroll
        for (int i = 0; i < 4; ++i) {
          const int r = wr * 64 + i * 16 + l16;
          const int pv = (kk * 4 + quad) ^ (r & 7);
          af[i] = *(const short8*)(smA + r * 128 + pv * 16);
        }
#pragma unroll
        for (int j = 0; j < 4; ++j) {
          const int r = wc * 64 + j * 16 + l16;
          const int pv = (kk * 4 + quad) ^ (r & 7);
          bf[j] = *(const short8*)(smB + r * 128 + pv * 16);
        }
#pragma unroll
        for (int i = 0; i < 4; ++i)
#pragma unroll
          for (int j = 0; j < 4; ++j)
            acc[i][j] = __builtin_amdgcn_mfma_f32_16x16x32_bf16(
                af[i], bf[j], acc[i][j], 0, 0, 0);
      }
    }

    // per-subtile row max / sum-exp.  C layout: col=l16, row=quad*4+reg.
    // The 16 lanes of a quad share rows -> butterfly over l16.
#pragma unroll
    for (int i = 0; i < 4; ++i) {
#pragma unroll
      for (int reg = 0; reg < 4; ++reg) {
        float mx = -INFINITY;
#pragma unroll
        for (int j = 0; j < 4; ++j) {
          const int col = col0 + wc * 64 + j * 16 + l16;
          if (col < V) mx = fmaxf(mx, acc[i][j][reg]);
        }
#pragma unroll
        for (int d = 1; d < 16; d <<= 1) mx = fmaxf(mx, __shfl_xor(mx, d, 64));
        float se = 0.0f;
#pragma unroll
        for (int j = 0; j < 4; ++j) {
          const int col = col0 + wc * 64 + j * 16 + l16;
          if (col < V) se += __expf(acc[i][j][reg] - mx);
        }
#pragma unroll
        for (int d = 1; d < 16; d <<= 1) se += __shfl_xor(se, d, 64);
        if (l16 == 0) {
          const int rloc = wr * 64 + i * 16 + quad * 4 + reg;
          red_m[wc][rloc] = mx;
          red_s[wc][rloc] = se;
        }
      }
    }
    __syncthreads();
    if (tid < BM) {  // thread tid owns block-row tid's running (m, s)
      const float m0 = red_m[0][tid], s0 = red_s[0][tid];
      const float m1 = red_m[1][tid], s1 = red_s[1][tid];
      const float tm = fmaxf(m0, m1);
      if (tm > -INFINITY) {
        const float ts = s0 * __expf(m0 - tm) + s1 * __expf(m1 - tm);
        const float nm = fmaxf(run_m, tm);
        run_s = run_s * __expf(run_m - nm) + ts * __expf(tm - nm);
        run_m = nm;
      }
    }
  }
  if (tid < BM) {
    m_part[(size_t)chunk * N + row0 + tid] = run_m;
    s_part[(size_t)chunk * N + row0 + tid] = run_s;
  }
}

// ---------------- merge partials, subtract target logit, mean ----------------
__global__ void finalize_kernel(const float* __restrict__ m_part,
                                const float* __restrict__ s_part,
                                const float* __restrict__ tgt,
                                const int* __restrict__ t,
                                float* __restrict__ out) {
  const int tid = threadIdx.x;
  double acc = 0.0;
  float cnt = 0.f;
  for (int row = tid; row < N; row += 256) {
    float M = -INFINITY;
    for (int ch = 0; ch < NC; ++ch) M = fmaxf(M, m_part[ch * N + row]);
    float S = 0.f;
    for (int ch = 0; ch < NC; ++ch) {
      const float m = m_part[ch * N + row];
      const float s = s_part[ch * N + row];
      if (s > 0.f) S += s * __expf(m - M);
    }
    const float lse = M + logf(S);
    if (t[row] != IGNORE_INDEX) {
      acc += (double)(lse - tgt[row]);
      cnt += 1.f;
    }
  }
  __shared__ double sacc[256];
  __shared__ float scnt[256];
  sacc[tid] = acc;
  scnt[tid] = cnt;
  __syncthreads();
  for (int s = 128; s > 0; s >>= 1) {
    if (tid < s) {
      sacc[tid] += sacc[tid + s];
      scnt[tid] += scnt[tid + s];
    }
    __syncthreads();
  }
  if (tid == 0) out[0] = (float)(sacc[0] / (double)fmaxf(scnt[0], 1.f));
}

extern "C" void kernel_launch(void* const* d_in, const int* in_sizes, int n_in,
                              void* d_out, int out_size, void* d_ws,
                              size_t ws_size, hipStream_t stream) {
  const float* e = (const float*)d_in[0];
  const float* c = (const float*)d_in[1];
  const int* t = (const int*)d_in[2];
  float* out = (float*)d_out;

  char* ws = (char*)d_ws;
  unsigned short* e_bf = (unsigned short*)ws;  // 16 MB
  size_t off = (size_t)N * D * 2;
  unsigned short* c_bf = (unsigned short*)(ws + off);  // 103 MB
  off += (size_t)V * D * 2;
  off = (off + 255) & ~(size_t)255;
  float* tgt = (float*)(ws + off);
  off += (size_t)N * 4;
  float* m_part = (float*)(ws + off);
  off += (size_t)NC * N * 4;
  float* s_part = (float*)(ws + off);
  off += (size_t)NC * N * 4;  // total ~120.8 MB of d_ws

  cast_bf16_kernel<<<(N * D / 4 + 255) / 256, 256, 0, stream>>>(e, e_bf, N * D / 4);
  cast_bf16_kernel<<<(V * D / 4 + 255) / 256, 256, 0, stream>>>(c, c_bf, V * D / 4);
  tgt_dot_kernel<<<N / 4, 256, 0, stream>>>(e, c, t, tgt);
  gemm_lse_kernel<<<dim3(NC, N / BM), 256, 0, stream>>>(e_bf, c_bf, m_part, s_part);
  finalize_kernel<<<1, 256, 0, stream>>>(m_part, s_part, tgt, t, out);
}

// Round 2
// 1406.165 us; speedup vs baseline: 1.1888x; 1.1888x over previous
//
#include <hip/hip_runtime.h>
#include <hip/hip_bf16.h>
#include <math.h>

#define IGNORE_INDEX (-100)

constexpr int N = 8192;
constexpr int D = 1024;
constexpr int V = 50257;

constexpr int BM = 128;
constexpr int BN = 128;
constexpr int BK = 64;
constexpr int NC = 16;                   // V-chunks (grid.x)
constexpr int SUBT = (V + BN - 1) / BN;  // 393 column subtiles

constexpr float LOG2E = 1.44269504088896340736f;
constexpr float LN2 = 0.69314718055994530942f;

typedef __attribute__((ext_vector_type(8))) short short8;
typedef __attribute__((ext_vector_type(4))) float floatx4;

__device__ __forceinline__ void gload_lds16(const void* g, void* l) {
  __builtin_amdgcn_global_load_lds(
      (const __attribute__((address_space(1))) void*)g,
      (__attribute__((address_space(3))) void*)l, 16, 0, 0);
}

__device__ __forceinline__ float fexp2(float x) {
#if __has_builtin(__builtin_amdgcn_exp2f)
  return __builtin_amdgcn_exp2f(x);
#else
  return exp2f(x);
#endif
}

// ---------------- fp32 -> bf16 cast (RNE); e is pre-scaled by log2(e) -------
__device__ __forceinline__ unsigned short f2bf(float f) {
  unsigned u = __float_as_uint(f);
  u += 0x7fffu + ((u >> 16) & 1u);
  return (unsigned short)(u >> 16);
}

constexpr int NE4 = N * D / 4;
constexpr int NC4 = V * D / 4;

__global__ void cast_both_kernel(const float* __restrict__ e,
                                 const float* __restrict__ c,
                                 unsigned short* __restrict__ e_bf,
                                 unsigned short* __restrict__ c_bf) {
  int idx = blockIdx.x * blockDim.x + threadIdx.x;
  if (idx < NE4) {
    const float4 v = ((const float4*)e)[idx];
    ushort4 o;
    o.x = f2bf(v.x * LOG2E);
    o.y = f2bf(v.y * LOG2E);
    o.z = f2bf(v.z * LOG2E);
    o.w = f2bf(v.w * LOG2E);
    ((ushort4*)e_bf)[idx] = o;
  } else {
    const int j = idx - NE4;
    if (j >= NC4) return;
    const float4 v = ((const float4*)c)[j];
    ushort4 o;
    o.x = f2bf(v.x); o.y = f2bf(v.y); o.z = f2bf(v.z); o.w = f2bf(v.w);
    ((ushort4*)c_bf)[j] = o;
  }
}

// ---------------- exact fp32 target-logit dot ----------------
__global__ void tgt_dot_kernel(const float* __restrict__ e,
                               const float* __restrict__ c,
                               const int* __restrict__ t,
                               float* __restrict__ tgt) {
  const int row = blockIdx.x * 4 + (threadIdx.x >> 6);
  const int lane = threadIdx.x & 63;
  int tr = t[row];
  if (tr == IGNORE_INDEX) tr = 0;
  const float4* ev = (const float4*)(e + (size_t)row * D);
  const float4* cv = (const float4*)(c + (size_t)tr * D);
  float s = 0.f;
#pragma unroll
  for (int k = 0; k < 4; ++k) {
    float4 a = ev[lane + k * 64];
    float4 b = cv[lane + k * 64];
    s += a.x * b.x + a.y * b.y + a.z * b.z + a.w * b.w;
  }
#pragma unroll
  for (int d = 1; d < 64; d <<= 1) s += __shfl_xor(s, d, 64);
  if (lane == 0) tgt[row] = s;
}

// ---------------- fused bf16 GEMM + online logsumexp partials ----------------
// A = e_bf16 (scaled by log2e) [N][D], B = c_bf16 [V][D], both K-major.
// Scaled-logit space: partials are (m2, s2) with lse = ln2*(m2 + log2(s2)).
__global__ __launch_bounds__(256) void gemm_lse_kernel(
    const unsigned short* __restrict__ A, const unsigned short* __restrict__ B,
    float* __restrict__ m_part, float* __restrict__ s_part) {
  __shared__ char smA[BM * BK * 2];  // 16 KB, rows of 8 x 16B vecs, XOR-swizzled
  __shared__ char smB[BN * BK * 2];  // 16 KB
  __shared__ float red_m[2][BM];
  __shared__ float red_s[2][BM];

  const int chunk = blockIdx.x;
  const int row0 = blockIdx.y * BM;
  const int tid = threadIdx.x;
  const int wave = tid >> 6;
  const int lane = tid & 63;
  const int wr = wave >> 1;  // wave row 0..1  (64-row half)
  const int wc = wave & 1;   // wave col 0..1  (64-col half)
  const int quad = lane >> 4;
  const int l16 = lane & 15;

  // staging: lane's LDS slot fixed (base+lane*16); pick global source so
  // physical vec pv holds logical vec lv = pv ^ (row&7) (XOR swizzle).
  const int lrow = lane >> 3;
  const int lvec_st = (lane & 7) ^ lrow;

  // per-thread online lse state: 16 (m,s) pairs, one per owned logit row
  // (row = wr*64 + i*16 + quad*4 + reg is subtile-invariant).
  float rm[16], rs[16];
#pragma unroll
  for (int x = 0; x < 16; ++x) { rm[x] = -1e30f; rs[x] = 0.0f; }

  const int nsub = (SUBT - chunk + NC - 1) / NC;  // round-robin subtiles
  for (int si = 0; si < nsub; ++si) {
    const int col0 = (chunk + si * NC) * BN;
    floatx4 acc[4][4];
#pragma unroll
    for (int i = 0; i < 4; ++i)
#pragma unroll
      for (int j = 0; j < 4; ++j) acc[i][j] = floatx4{0.f, 0.f, 0.f, 0.f};

    for (int ks = 0; ks < D / BK; ++ks) {
      const int k0 = ks * BK;
      __syncthreads();  // previous ds_reads done before overwrite
#pragma unroll
      for (int cc = 0; cc < 4; ++cc) {
        const int ch = wave * 4 + cc;
        const int arow = row0 + ch * 8 + lrow;
        gload_lds16((const char*)(A + (size_t)arow * D + k0) + lvec_st * 16,
                    smA + ch * 1024 + lane * 16);
        int brow = col0 + ch * 8 + lrow;
        if (brow >= V) brow = V - 1;  // dup last row; masked in stats
        gload_lds16((const char*)(B + (size_t)brow * D + k0) + lvec_st * 16,
                    smB + ch * 1024 + lane * 16);
      }
      __syncthreads();
#pragma unroll
      for (int kk = 0; kk < 2; ++kk) {
        short8 af[4], bf[4];
#pragma unroll
        for (int i = 0; i < 4; ++i) {
          const int r = wr * 64 + i * 16 + l16;
          const int pv = (kk * 4 + quad) ^ (r & 7);
          af[i] = *(const short8*)(smA + r * 128 + pv * 16);
        }
#pragma unroll
        for (int j = 0; j < 4; ++j) {
          const int r = wc * 64 + j * 16 + l16;
          const int pv = (kk * 4 + quad) ^ (r & 7);
          bf[j] = *(const short8*)(smB + r * 128 + pv * 16);
        }
#pragma unroll
        for (int i = 0; i < 4; ++i)
#pragma unroll
          for (int j = 0; j < 4; ++j)
            acc[i][j] = __builtin_amdgcn_mfma_f32_16x16x32_bf16(
                af[i], bf[j], acc[i][j], 0, 0, 0);
      }
    }

    // per-subtile per-thread online update — no shuffles, no barriers.
    // C layout: col = l16, row = quad*4+reg.
    const bool edge = (col0 + BN > V);  // wave-uniform (only subtile 392)
#pragma unroll
    for (int i = 0; i < 4; ++i) {
#pragma unroll
      for (int reg = 0; reg < 4; ++reg) {
        float v0 = acc[i][0][reg], v1 = acc[i][1][reg];
        float v2 = acc[i][2][reg], v3 = acc[i][3][reg];
        if (edge) {
          const int cb = col0 + wc * 64 + l16;
          if (cb + 0 >= V) v0 = -INFINITY;
          if (cb + 16 >= V) v1 = -INFINITY;
          if (cb + 32 >= V) v2 = -INFINITY;
          if (cb + 48 >= V) v3 = -INFINITY;
        }
        const int x = i * 4 + reg;
        const float mx = fmaxf(fmaxf(v0, v1), fmaxf(v2, v3));
        const float nm = fmaxf(rm[x], mx);
        rs[x] = rs[x] * fexp2(rm[x] - nm) + fexp2(v0 - nm) + fexp2(v1 - nm) +
                fexp2(v2 - nm) + fexp2(v3 - nm);
        rm[x] = nm;
      }
    }
  }

  // once-per-kernel reduction: butterfly over the 16 lanes sharing each row
#pragma unroll
  for (int x = 0; x < 16; ++x) {
    float m = rm[x], s = rs[x];
#pragma unroll
    for (int d = 1; d < 16; d <<= 1) {
      const float om = __shfl_xor(m, d, 64);
      const float os = __shfl_xor(s, d, 64);
      const float nm = fmaxf(m, om);
      s = s * fexp2(m - nm) + os * fexp2(om - nm);
      m = nm;
    }
    if (l16 == 0) {
      const int i = x >> 2, reg = x & 3;
      const int rloc = wr * 64 + i * 16 + quad * 4 + reg;
      red_m[wc][rloc] = m;
      red_s[wc][rloc] = s;
    }
  }
  __syncthreads();
  if (tid < BM) {  // merge the two column-half waves, write chunk partials
    const float m0 = red_m[0][tid], s0 = red_s[0][tid];
    const float m1 = red_m[1][tid], s1 = red_s[1][tid];
    const float tm = fmaxf(m0, m1);
    const float ts = s0 * fexp2(m0 - tm) + s1 * fexp2(m1 - tm);
    m_part[(size_t)chunk * N + row0 + tid] = tm;
    s_part[(size_t)chunk * N + row0 + tid] = ts;
  }
}

// ---------------- finalize: merge chunk partials, subtract target, mean -----
__global__ void finalize1_kernel(const float* __restrict__ m_part,
                                 const float* __restrict__ s_part,
                                 const float* __restrict__ tgt,
                                 const int* __restrict__ t,
                                 double* __restrict__ fin) {
  const int tid = threadIdx.x;
  const int row = blockIdx.x * 256 + tid;
  float M = -1e30f;
#pragma unroll
  for (int ch = 0; ch < NC; ++ch) M = fmaxf(M, m_part[ch * N + row]);
  float S = 0.f;
#pragma unroll
  for (int ch = 0; ch < NC; ++ch)
    S += s_part[ch * N + row] * fexp2(m_part[ch * N + row] - M);
  const float lse = LN2 * (M + log2f(S));  // back to natural-log space
  double nll = 0.0;
  double cnt = 0.0;
  if (t[row] != IGNORE_INDEX) {
    nll = (double)(lse - tgt[row]);
    cnt = 1.0;
  }
  __shared__ double sacc[256];
  __shared__ double scnt[256];
  sacc[tid] = nll;
  scnt[tid] = cnt;
  __syncthreads();
  for (int s = 128; s > 0; s >>= 1) {
    if (tid < s) {
      sacc[tid] += sacc[tid + s];
      scnt[tid] += scnt[tid + s];
    }
    __syncthreads();
  }
  if (tid == 0) {
    fin[blockIdx.x * 2] = sacc[0];
    fin[blockIdx.x * 2 + 1] = scnt[0];
  }
}

__global__ void finalize2_kernel(const double* __restrict__ fin,
                                 float* __restrict__ out) {
  const int tid = threadIdx.x;  // 64 threads, 32 active
  __shared__ double sa[64], sc[64];
  sa[tid] = (tid < 32) ? fin[tid * 2] : 0.0;
  sc[tid] = (tid < 32) ? fin[tid * 2 + 1] : 0.0;
  __syncthreads();
  for (int s = 32; s > 0; s >>= 1) {
    if (tid < s) {
      sa[tid] += sa[tid + s];
      sc[tid] += sc[tid + s];
    }
    __syncthreads();
  }
  if (tid == 0) out[0] = (float)(sa[0] / fmax(sc[0], 1.0));
}

extern "C" void kernel_launch(void* const* d_in, const int* in_sizes, int n_in,
                              void* d_out, int out_size, void* d_ws,
                              size_t ws_size, hipStream_t stream) {
  const float* e = (const float*)d_in[0];
  const float* c = (const float*)d_in[1];
  const int* t = (const int*)d_in[2];
  float* out = (float*)d_out;

  char* ws = (char*)d_ws;
  unsigned short* e_bf = (unsigned short*)ws;  // 16 MB (scaled by log2e)
  size_t off = (size_t)N * D * 2;
  unsigned short* c_bf = (unsigned short*)(ws + off);  // 103 MB
  off += (size_t)V * D * 2;
  off = (off + 255) & ~(size_t)255;
  float* tgt = (float*)(ws + off);
  off += (size_t)N * 4;
  float* m_part = (float*)(ws + off);
  off += (size_t)NC * N * 4;
  float* s_part = (float*)(ws + off);
  off += (size_t)NC * N * 4;
  double* fin = (double*)(ws + off);
  off += 32 * 2 * sizeof(double);  // total ~121 MB of d_ws

  const int total4 = NE4 + NC4;
  cast_both_kernel<<<(total4 + 255) / 256, 256, 0, stream>>>(e, c, e_bf, c_bf);
  tgt_dot_kernel<<<N / 4, 256, 0, stream>>>(e, c, t, tgt);
  gemm_lse_kernel<<<dim3(NC, N / BM), 256, 0, stream>>>(e_bf, c_bf, m_part,
                                                        s_part);
  finalize1_kernel<<<32, 256, 0, stream>>>(m_part, s_part, tgt, t, fin);
  finalize2_kernel<<<1, 64, 0, stream>>>(fin, out);
}

// Round 3
// 1091.001 us; speedup vs baseline: 1.5322x; 1.2889x over previous
//
#include <hip/hip_runtime.h>
#include <hip/hip_bf16.h>
#include <math.h>

#define IGNORE_INDEX (-100)

constexpr int N = 8192;
constexpr int D = 1024;
constexpr int V = 50257;

constexpr int BM = 128;
constexpr int BN = 256;  // pair of 128-col subtiles per K-pass
constexpr int BK = 64;
constexpr int NC = 16;                   // V-chunks (grid.x)
constexpr int SUBT = (V + BN - 1) / BN;  // 197 column tiles

constexpr float LOG2E = 1.44269504088896340736f;
constexpr float LN2 = 0.69314718055994530942f;

typedef __attribute__((ext_vector_type(8))) short short8;
typedef __attribute__((ext_vector_type(4))) float floatx4;

__device__ __forceinline__ void gload_lds16(const void* g, void* l) {
  __builtin_amdgcn_global_load_lds(
      (const __attribute__((address_space(1))) void*)g,
      (__attribute__((address_space(3))) void*)l, 16, 0, 0);
}

__device__ __forceinline__ float fexp2(float x) {
#if __has_builtin(__builtin_amdgcn_exp2f)
  return __builtin_amdgcn_exp2f(x);
#else
  return exp2f(x);
#endif
}

// ---------------- fp32 -> bf16 cast (RNE); e pre-scaled by log2(e) ----------
__device__ __forceinline__ unsigned short f2bf(float f) {
  unsigned u = __float_as_uint(f);
  u += 0x7fffu + ((u >> 16) & 1u);
  return (unsigned short)(u >> 16);
}

constexpr int NE4 = N * D / 4;
constexpr int NC4 = V * D / 4;
constexpr int CAST_BLOCKS = (NE4 + NC4) / 256;  // 58449, exact
constexpr int TGT_BLOCKS = N / 4;               // 2048

// Fused: bf16 casts (blocks [0, CAST_BLOCKS)) + exact fp32 target-logit dot
// (blocks [CAST_BLOCKS, CAST_BLOCKS+TGT_BLOCKS)). Independent work items.
__global__ void prep_kernel(const float* __restrict__ e,
                            const float* __restrict__ c,
                            const int* __restrict__ t,
                            unsigned short* __restrict__ e_bf,
                            unsigned short* __restrict__ c_bf,
                            float* __restrict__ tgt) {
  if (blockIdx.x < CAST_BLOCKS) {
    const int idx = blockIdx.x * 256 + threadIdx.x;
    if (idx < NE4) {
      const float4 v = ((const float4*)e)[idx];
      ushort4 o;
      o.x = f2bf(v.x * LOG2E);
      o.y = f2bf(v.y * LOG2E);
      o.z = f2bf(v.z * LOG2E);
      o.w = f2bf(v.w * LOG2E);
      ((ushort4*)e_bf)[idx] = o;
    } else {
      const int j = idx - NE4;
      const float4 v = ((const float4*)c)[j];
      ushort4 o;
      o.x = f2bf(v.x); o.y = f2bf(v.y); o.z = f2bf(v.z); o.w = f2bf(v.w);
      ((ushort4*)c_bf)[j] = o;
    }
  } else {
    const int row = (blockIdx.x - CAST_BLOCKS) * 4 + (threadIdx.x >> 6);
    const int lane = threadIdx.x & 63;
    int tr = t[row];
    if (tr == IGNORE_INDEX) tr = 0;
    const float4* ev = (const float4*)(e + (size_t)row * D);
    const float4* cv = (const float4*)(c + (size_t)tr * D);
    float s = 0.f;
#pragma unroll
    for (int k = 0; k < 4; ++k) {
      float4 a = ev[lane + k * 64];
      float4 b = cv[lane + k * 64];
      s += a.x * b.x + a.y * b.y + a.z * b.z + a.w * b.w;
    }
#pragma unroll
    for (int d = 1; d < 64; d <<= 1) s += __shfl_xor(s, d, 64);
    if (lane == 0) tgt[row] = s;
  }
}

// ---------------- fused bf16 GEMM + online logsumexp partials ----------------
// A = e_bf16 (scaled by log2e) [N][D], B = c_bf16 [V][D], both K-major.
// Scaled-logit space: partials are (m2, s2) with lse = ln2*(m2 + log2(s2)).
// 128x256 tile: acc[4][8] per wave (waves 2x2, each 64 rows x 128 cols).
__global__ __launch_bounds__(256, 2) void gemm_lse_kernel(
    const unsigned short* __restrict__ A, const unsigned short* __restrict__ B,
    float* __restrict__ m_part, float* __restrict__ s_part) {
  __shared__ char smA[BM * BK * 2];  // 16 KB, XOR-swizzled rows of 8x16B vecs
  __shared__ char smB[BN * BK * 2];  // 32 KB
  __shared__ float red_m[2][BM];
  __shared__ float red_s[2][BM];

  const int chunk = blockIdx.x;
  const int row0 = blockIdx.y * BM;
  const int tid = threadIdx.x;
  const int wave = tid >> 6;
  const int lane = tid & 63;
  const int wr = wave >> 1;  // row half (64 rows)
  const int wc = wave & 1;   // col half (128 cols)
  const int quad = lane >> 4;
  const int l16 = lane & 15;

  // staging: lane's LDS slot fixed (base+lane*16); pick global source so
  // physical vec pv holds logical vec lv = pv ^ (row&7) (XOR swizzle).
  const int lrow = lane >> 3;
  const int lvec_st = (lane & 7) ^ lrow;

  // per-thread online lse state: 16 (m,s) pairs, one per owned logit row
  // (row = wr*64 + i*16 + quad*4 + reg is subtile-invariant; BM unchanged
  //  so state stays 32 VGPRs — this is why we grew BN, not BM).
  float rm[16], rs[16];
#pragma unroll
  for (int x = 0; x < 16; ++x) { rm[x] = -1e30f; rs[x] = 0.0f; }

  const int nsub = (SUBT - chunk + NC - 1) / NC;  // round-robin col tiles
  for (int si = 0; si < nsub; ++si) {
    const int col0 = (chunk + si * NC) * BN;
    floatx4 acc[4][8];
#pragma unroll
    for (int i = 0; i < 4; ++i)
#pragma unroll
      for (int j = 0; j < 8; ++j) acc[i][j] = floatx4{0.f, 0.f, 0.f, 0.f};

    for (int ks = 0; ks < D / BK; ++ks) {
      const int k0 = ks * BK;
      __syncthreads();  // previous ds_reads done before overwrite
#pragma unroll
      for (int cc = 0; cc < 4; ++cc) {  // A: 16 chunks x 8 rows = 128
        const int ch = wave * 4 + cc;
        const int arow = row0 + ch * 8 + lrow;
        gload_lds16((const char*)(A + (size_t)arow * D + k0) + lvec_st * 16,
                    smA + ch * 1024 + lane * 16);
      }
#pragma unroll
      for (int cc = 0; cc < 8; ++cc) {  // B: 32 chunks x 8 rows = 256
        const int ch = wave * 8 + cc;
        int brow = col0 + ch * 8 + lrow;
        if (brow >= V) brow = V - 1;  // dup last row; masked in stats
        gload_lds16((const char*)(B + (size_t)brow * D + k0) + lvec_st * 16,
                    smB + ch * 1024 + lane * 16);
      }
      __syncthreads();
#pragma unroll
      for (int kk = 0; kk < 2; ++kk) {
        short8 af[4], bf[8];
#pragma unroll
        for (int i = 0; i < 4; ++i) {
          const int r = wr * 64 + i * 16 + l16;
          const int pv = (kk * 4 + quad) ^ (r & 7);
          af[i] = *(const short8*)(smA + r * 128 + pv * 16);
        }
#pragma unroll
        for (int j = 0; j < 8; ++j) {
          const int r = wc * 128 + j * 16 + l16;
          const int pv = (kk * 4 + quad) ^ (r & 7);
          bf[j] = *(const short8*)(smB + r * 128 + pv * 16);
        }
#pragma unroll
        for (int j = 0; j < 8; ++j)
#pragma unroll
          for (int i = 0; i < 4; ++i)
            acc[i][j] = __builtin_amdgcn_mfma_f32_16x16x32_bf16(
                af[i], bf[j], acc[i][j], 0, 0, 0);
      }
    }

    // per-tile per-thread online update — no shuffles, no barriers.
    // C layout: col = l16, row = quad*4+reg.
    const bool edge = (col0 + BN > V);  // wave-uniform (only the last tile)
#pragma unroll
    for (int i = 0; i < 4; ++i) {
#pragma unroll
      for (int reg = 0; reg < 4; ++reg) {
        float v[8];
#pragma unroll
        for (int j = 0; j < 8; ++j) v[j] = acc[i][j][reg];
        if (edge) {
          const int cb = col0 + wc * 128 + l16;
#pragma unroll
          for (int j = 0; j < 8; ++j)
            if (cb + j * 16 >= V) v[j] = -INFINITY;
        }
        float mx = v[0];
#pragma unroll
        for (int j = 1; j < 8; ++j) mx = fmaxf(mx, v[j]);
        const int x = i * 4 + reg;
        const float nm = fmaxf(rm[x], mx);
        float s = rs[x] * fexp2(rm[x] - nm);
#pragma unroll
        for (int j = 0; j < 8; ++j) s += fexp2(v[j] - nm);
        rs[x] = s;
        rm[x] = nm;
      }
    }
  }

  // once-per-kernel reduction: butterfly over the 16 lanes sharing each row
#pragma unroll
  for (int x = 0; x < 16; ++x) {
    float m = rm[x], s = rs[x];
#pragma unroll
    for (int d = 1; d < 16; d <<= 1) {
      const float om = __shfl_xor(m, d, 64);
      const float os = __shfl_xor(s, d, 64);
      const float nm = fmaxf(m, om);
      s = s * fexp2(m - nm) + os * fexp2(om - nm);
      m = nm;
    }
    if (l16 == 0) {
      const int i = x >> 2, reg = x & 3;
      const int rloc = wr * 64 + i * 16 + quad * 4 + reg;
      red_m[wc][rloc] = m;
      red_s[wc][rloc] = s;
    }
  }
  __syncthreads();
  if (tid < BM) {  // merge the two column-half waves, write chunk partials
    const float m0 = red_m[0][tid], s0 = red_s[0][tid];
    const float m1 = red_m[1][tid], s1 = red_s[1][tid];
    const float tm = fmaxf(m0, m1);
    const float ts = s0 * fexp2(m0 - tm) + s1 * fexp2(m1 - tm);
    m_part[(size_t)chunk * N + row0 + tid] = tm;
    s_part[(size_t)chunk * N + row0 + tid] = ts;
  }
}

// ---------------- finalize: merge chunk partials, subtract target, mean -----
__global__ void finalize1_kernel(const float* __restrict__ m_part,
                                 const float* __restrict__ s_part,
                                 const float* __restrict__ tgt,
                                 const int* __restrict__ t,
                                 double* __restrict__ fin) {
  const int tid = threadIdx.x;
  const int row = blockIdx.x * 256 + tid;
  float M = -1e30f;
#pragma unroll
  for (int ch = 0; ch < NC; ++ch) M = fmaxf(M, m_part[ch * N + row]);
  float S = 0.f;
#pragma unroll
  for (int ch = 0; ch < NC; ++ch)
    S += s_part[ch * N + row] * fexp2(m_part[ch * N + row] - M);
  const float lse = LN2 * (M + log2f(S));  // back to natural-log space
  double nll = 0.0;
  double cnt = 0.0;
  if (t[row] != IGNORE_INDEX) {
    nll = (double)(lse - tgt[row]);
    cnt = 1.0;
  }
  __shared__ double sacc[256];
  __shared__ double scnt[256];
  sacc[tid] = nll;
  scnt[tid] = cnt;
  __syncthreads();
  for (int s = 128; s > 0; s >>= 1) {
    if (tid < s) {
      sacc[tid] += sacc[tid + s];
      scnt[tid] += scnt[tid + s];
    }
    __syncthreads();
  }
  if (tid == 0) {
    fin[blockIdx.x * 2] = sacc[0];
    fin[blockIdx.x * 2 + 1] = scnt[0];
  }
}

__global__ void finalize2_kernel(const double* __restrict__ fin,
                                 float* __restrict__ out) {
  const int tid = threadIdx.x;  // 64 threads, 32 active
  __shared__ double sa[64], sc[64];
  sa[tid] = (tid < 32) ? fin[tid * 2] : 0.0;
  sc[tid] = (tid < 32) ? fin[tid * 2 + 1] : 0.0;
  __syncthreads();
  for (int s = 32; s > 0; s >>= 1) {
    if (tid < s) {
      sa[tid] += sa[tid + s];
      sc[tid] += sc[tid + s];
    }
    __syncthreads();
  }
  if (tid == 0) out[0] = (float)(sa[0] / fmax(sc[0], 1.0));
}

extern "C" void kernel_launch(void* const* d_in, const int* in_sizes, int n_in,
                              void* d_out, int out_size, void* d_ws,
                              size_t ws_size, hipStream_t stream) {
  const float* e = (const float*)d_in[0];
  const float* c = (const float*)d_in[1];
  const int* t = (const int*)d_in[2];
  float* out = (float*)d_out;

  char* ws = (char*)d_ws;
  unsigned short* e_bf = (unsigned short*)ws;  // 16 MB (scaled by log2e)
  size_t off = (size_t)N * D * 2;
  unsigned short* c_bf = (unsigned short*)(ws + off);  // 103 MB
  off += (size_t)V * D * 2;
  off = (off + 255) & ~(size_t)255;
  float* tgt = (float*)(ws + off);
  off += (size_t)N * 4;
  float* m_part = (float*)(ws + off);
  off += (size_t)NC * N * 4;
  float* s_part = (float*)(ws + off);
  off += (size_t)NC * N * 4;
  double* fin = (double*)(ws + off);
  off += 32 * 2 * sizeof(double);  // total ~121 MB of d_ws

  prep_kernel<<<CAST_BLOCKS + TGT_BLOCKS, 256, 0, stream>>>(e, c, t, e_bf,
                                                            c_bf, tgt);
  gemm_lse_kernel<<<dim3(NC, N / BM), 256, 0, stream>>>(e_bf, c_bf, m_part,
                                                        s_part);
  finalize1_kernel<<<32, 256, 0, stream>>>(m_part, s_part, tgt, t, fin);
  finalize2_kernel<<<1, 64, 0, stream>>>(fin, out);
}

// Round 4
// 1015.806 us; speedup vs baseline: 1.6456x; 1.0740x over previous
//
#include <hip/hip_runtime.h>
#include <hip/hip_bf16.h>
#include <math.h>

#define IGNORE_INDEX (-100)

constexpr int N = 8192;
constexpr int D = 1024;
constexpr int V = 50257;

constexpr int BM = 128;
constexpr int BN = 256;
constexpr int BK = 128;                  // one 16x16x128 MFMA K-depth per ks
constexpr int NC = 16;                   // V-chunks (grid.x)
constexpr int SUBT = (V + BN - 1) / BN;  // 197 column tiles

constexpr float LOG2E = 1.44269504088896340736f;
constexpr float LN2 = 0.69314718055994530942f;

typedef __attribute__((ext_vector_type(8))) int int8v;
typedef __attribute__((ext_vector_type(4))) float floatx4;

__device__ __forceinline__ void gload_lds16(const void* g, void* l) {
  __builtin_amdgcn_global_load_lds(
      (const __attribute__((address_space(1))) void*)g,
      (__attribute__((address_space(3))) void*)l, 16, 0, 0);
}

__device__ __forceinline__ float fexp2(float x) {
#if __has_builtin(__builtin_amdgcn_exp2f)
  return __builtin_amdgcn_exp2f(x);
#else
  return exp2f(x);
#endif
}

// ---------------- prep: fp8(e4m3, OCP) casts + exact fp32 target dot --------
// e is pre-scaled by log2(e) so the GEMM computes base-2 logits.
constexpr int E8 = N * D / 8;         // 8-float work items for e
constexpr int C8 = V * D / 8;         // for c
constexpr int EB = E8 / 256;          // 4096 blocks (exact)
constexpr int CB = (C8 + 255) / 256;  // 25129 blocks
constexpr int TGT_BLOCKS = N / 4;     // 2048 blocks

__device__ __forceinline__ unsigned int pk4_fp8(float a, float b, float c,
                                                float d) {
  int p = __builtin_amdgcn_cvt_pk_fp8_f32(a, b, 0, false);
  p = __builtin_amdgcn_cvt_pk_fp8_f32(c, d, p, true);
  return (unsigned int)p;
}

__global__ void prep_kernel(const float* __restrict__ e,
                            const float* __restrict__ c,
                            const int* __restrict__ t,
                            unsigned int* __restrict__ e8,
                            unsigned int* __restrict__ c8,
                            float* __restrict__ tgt) {
  const int b = blockIdx.x;
  if (b < EB) {
    const int idx = b * 256 + threadIdx.x;  // one 8-float unit
    const float4 v0 = ((const float4*)e)[idx * 2];
    const float4 v1 = ((const float4*)e)[idx * 2 + 1];
    uint2 o;
    o.x = pk4_fp8(v0.x * LOG2E, v0.y * LOG2E, v0.z * LOG2E, v0.w * LOG2E);
    o.y = pk4_fp8(v1.x * LOG2E, v1.y * LOG2E, v1.z * LOG2E, v1.w * LOG2E);
    ((uint2*)e8)[idx] = o;
  } else if (b < EB + CB) {
    const int idx = (b - EB) * 256 + threadIdx.x;
    if (idx < C8) {
      const float4 v0 = ((const float4*)c)[idx * 2];
      const float4 v1 = ((const float4*)c)[idx * 2 + 1];
      uint2 o;
      o.x = pk4_fp8(v0.x, v0.y, v0.z, v0.w);
      o.y = pk4_fp8(v1.x, v1.y, v1.z, v1.w);
      ((uint2*)c8)[idx] = o;
    }
  } else {
    const int row = (b - EB - CB) * 4 + (threadIdx.x >> 6);
    const int lane = threadIdx.x & 63;
    int tr = t[row];
    if (tr == IGNORE_INDEX) tr = 0;
    const float4* ev = (const float4*)(e + (size_t)row * D);
    const float4* cv = (const float4*)(c + (size_t)tr * D);
    float s = 0.f;
#pragma unroll
    for (int k = 0; k < 4; ++k) {
      float4 a = ev[lane + k * 64];
      float4 bb = cv[lane + k * 64];
      s += a.x * bb.x + a.y * bb.y + a.z * bb.z + a.w * bb.w;
    }
#pragma unroll
    for (int d = 1; d < 64; d <<= 1) s += __shfl_xor(s, d, 64);
    if (lane == 0) tgt[row] = s;
  }
}

// ---------------- fused fp8 GEMM + online logsumexp partials ----------------
// A = e_fp8 (log2e-scaled) [N][D], B = c_fp8 [V][D], K-major bytes.
// MFMA: 16x16x128 f8f6f4, fmt=fp8 both, scales fixed to 1 (all bytes 0x7F).
// A frags load direct from global (L2-hot); B staged to LDS (2x reuse).
// Partials (m2, s2) in base-2 space: lse = ln2*(m2 + log2(s2)).
__global__ __launch_bounds__(256, 2) void gemm_lse_kernel(
    const unsigned char* __restrict__ A, const unsigned char* __restrict__ B,
    float* __restrict__ m_part, float* __restrict__ s_part) {
  __shared__ char smB[BN * BK];  // 32 KB, XOR-swizzled rows of 8x16B vecs
  __shared__ float red_m[2][BM];
  __shared__ float red_s[2][BM];

  const int chunk = blockIdx.x;
  const int row0 = blockIdx.y * BM;
  const int tid = threadIdx.x;
  const int wave = tid >> 6;
  const int lane = tid & 63;
  const int wr = wave >> 1;  // row half (64 rows)
  const int wc = wave & 1;   // col half (128 cols)
  const int quad = lane >> 4;
  const int l16 = lane & 15;

  // B staging: lane's LDS slot fixed (chunk base + lane*16); source vec
  // chosen so physical vec pv holds logical vec pv ^ (row&7).
  const int lrow = lane >> 3;
  const int lvec_st = (lane & 7) ^ lrow;

  // A fragment base: row = row0 + wr*64 + i*16 + l16, k = quad*32 + 0..31
  // (16x16x128 A layout: row = lane&15, k = (lane>>4)*32 + j, contiguous)
  const int4* abase =
      (const int4*)(A + (size_t)(row0 + wr * 64 + l16) * D + quad * 32);

  // per-thread online lse state: 16 (m,s) pairs (row = wr*64+i*16+quad*4+reg
  // is tile-invariant)
  float rm[16], rs[16];
#pragma unroll
  for (int x = 0; x < 16; ++x) { rm[x] = -1e30f; rs[x] = 0.0f; }

  const int nsub = (SUBT - chunk + NC - 1) / NC;  // round-robin col tiles
  for (int si = 0; si < nsub; ++si) {
    const int col0 = (chunk + si * NC) * BN;
    floatx4 acc[4][8];
#pragma unroll
    for (int i = 0; i < 4; ++i)
#pragma unroll
      for (int j = 0; j < 8; ++j) acc[i][j] = floatx4{0.f, 0.f, 0.f, 0.f};

    for (int ks = 0; ks < D / BK; ++ks) {
      __syncthreads();  // previous ds_reads done before overwrite
#pragma unroll
      for (int cc = 0; cc < 8; ++cc) {  // B: 32 chunks x 8 rows = 256
        const int ch = wave * 8 + cc;
        int brow = col0 + ch * 8 + lrow;
        if (brow >= V) brow = V - 1;  // dup last row; masked in stats
        gload_lds16(B + (size_t)brow * D + ks * BK + lvec_st * 16,
                    smB + ch * 1024 + lane * 16);
      }
      // A frags from global — latency hides under the B staging drain
      int8v af[4];
#pragma unroll
      for (int i = 0; i < 4; ++i) {
        const int4 lo = abase[i * 1024 + ks * 8];
        const int4 hi = abase[i * 1024 + ks * 8 + 1];
        af[i][0] = lo.x; af[i][1] = lo.y; af[i][2] = lo.z; af[i][3] = lo.w;
        af[i][4] = hi.x; af[i][5] = hi.y; af[i][6] = hi.z; af[i][7] = hi.w;
      }
      __syncthreads();  // B visible
#pragma unroll
      for (int jh = 0; jh < 2; ++jh) {  // halves cap live bf regs at 32
        int8v bf[4];
#pragma unroll
        for (int jj = 0; jj < 4; ++jj) {
          const int cr = wc * 128 + (jh * 4 + jj) * 16 + l16;
          const char* base = smB + cr * 128;
          const int4 lo =
              *(const int4*)(base + (((quad * 2) ^ (cr & 7)) * 16));
          const int4 hi =
              *(const int4*)(base + (((quad * 2 + 1) ^ (cr & 7)) * 16));
          bf[jj][0] = lo.x; bf[jj][1] = lo.y; bf[jj][2] = lo.z; bf[jj][3] = lo.w;
          bf[jj][4] = hi.x; bf[jj][5] = hi.y; bf[jj][6] = hi.z; bf[jj][7] = hi.w;
        }
#pragma unroll
        for (int jj = 0; jj < 4; ++jj)
#pragma unroll
          for (int i = 0; i < 4; ++i)
            acc[i][jh * 4 + jj] = __builtin_amdgcn_mfma_scale_f32_16x16x128_f8f6f4(
                af[i], bf[jj], acc[i][jh * 4 + jj], 0, 0,  // cbsz=fp8, blgp=fp8
                0, 0x7F7F7F7F, 0, 0x7F7F7F7F);  // scales = 2^0 (any layout)
      }
    }

    // per-tile per-thread online update. C layout: col=l16, row=quad*4+reg.
    const bool edge = (col0 + BN > V);  // wave-uniform (last tile only)
#pragma unroll
    for (int i = 0; i < 4; ++i) {
#pragma unroll
      for (int reg = 0; reg < 4; ++reg) {
        float v[8];
#pragma unroll
        for (int j = 0; j < 8; ++j) v[j] = acc[i][j][reg];
        if (edge) {
          const int cb = col0 + wc * 128 + l16;
#pragma unroll
          for (int j = 0; j < 8; ++j)
            if (cb + j * 16 >= V) v[j] = -INFINITY;
        }
        float mx = v[0];
#pragma unroll
        for (int j = 1; j < 8; ++j) mx = fmaxf(mx, v[j]);
        const int x = i * 4 + reg;
        const float nm = fmaxf(rm[x], mx);
        float s = rs[x] * fexp2(rm[x] - nm);
#pragma unroll
        for (int j = 0; j < 8; ++j) s += fexp2(v[j] - nm);
        rs[x] = s;
        rm[x] = nm;
      }
    }
  }

  // once-per-kernel reduction: butterfly over the 16 lanes sharing each row
#pragma unroll
  for (int x = 0; x < 16; ++x) {
    float m = rm[x], s = rs[x];
#pragma unroll
    for (int d = 1; d < 16; d <<= 1) {
      const float om = __shfl_xor(m, d, 64);
      const float os = __shfl_xor(s, d, 64);
      const float nm = fmaxf(m, om);
      s = s * fexp2(m - nm) + os * fexp2(om - nm);
      m = nm;
    }
    if (l16 == 0) {
      const int i = x >> 2, reg = x & 3;
      const int rloc = wr * 64 + i * 16 + quad * 4 + reg;
      red_m[wc][rloc] = m;
      red_s[wc][rloc] = s;
    }
  }
  __syncthreads();
  if (tid < BM) {  // merge the two column-half waves, write chunk partials
    const float m0 = red_m[0][tid], s0 = red_s[0][tid];
    const float m1 = red_m[1][tid], s1 = red_s[1][tid];
    const float tm = fmaxf(m0, m1);
    const float ts = s0 * fexp2(m0 - tm) + s1 * fexp2(m1 - tm);
    m_part[(size_t)chunk * N + row0 + tid] = tm;
    s_part[(size_t)chunk * N + row0 + tid] = ts;
  }
}

// ---------------- finalize: merge chunk partials, subtract target, mean -----
__global__ void finalize1_kernel(const float* __restrict__ m_part,
                                 const float* __restrict__ s_part,
                                 const float* __restrict__ tgt,
                                 const int* __restrict__ t,
                                 double* __restrict__ fin) {
  const int tid = threadIdx.x;
  const int row = blockIdx.x * 256 + tid;
  float M = -1e30f;
#pragma unroll
  for (int ch = 0; ch < NC; ++ch) M = fmaxf(M, m_part[ch * N + row]);
  float S = 0.f;
#pragma unroll
  for (int ch = 0; ch < NC; ++ch)
    S += s_part[ch * N + row] * fexp2(m_part[ch * N + row] - M);
  const float lse = LN2 * (M + log2f(S));  // back to natural-log space
  double nll = 0.0;
  double cnt = 0.0;
  if (t[row] != IGNORE_INDEX) {
    nll = (double)(lse - tgt[row]);
    cnt = 1.0;
  }
  __shared__ double sacc[256];
  __shared__ double scnt[256];
  sacc[tid] = nll;
  scnt[tid] = cnt;
  __syncthreads();
  for (int s = 128; s > 0; s >>= 1) {
    if (tid < s) {
      sacc[tid] += sacc[tid + s];
      scnt[tid] += scnt[tid + s];
    }
    __syncthreads();
  }
  if (tid == 0) {
    fin[blockIdx.x * 2] = sacc[0];
    fin[blockIdx.x * 2 + 1] = scnt[0];
  }
}

__global__ void finalize2_kernel(const double* __restrict__ fin,
                                 float* __restrict__ out) {
  const int tid = threadIdx.x;  // 64 threads, 32 active
  __shared__ double sa[64], sc[64];
  sa[tid] = (tid < 32) ? fin[tid * 2] : 0.0;
  sc[tid] = (tid < 32) ? fin[tid * 2 + 1] : 0.0;
  __syncthreads();
  for (int s = 32; s > 0; s >>= 1) {
    if (tid < s) {
      sa[tid] += sa[tid + s];
      sc[tid] += sc[tid + s];
    }
    __syncthreads();
  }
  if (tid == 0) out[0] = (float)(sa[0] / fmax(sc[0], 1.0));
}

extern "C" void kernel_launch(void* const* d_in, const int* in_sizes, int n_in,
                              void* d_out, int out_size, void* d_ws,
                              size_t ws_size, hipStream_t stream) {
  const float* e = (const float*)d_in[0];
  const float* c = (const float*)d_in[1];
  const int* t = (const int*)d_in[2];
  float* out = (float*)d_out;

  char* ws = (char*)d_ws;
  unsigned char* e8 = (unsigned char*)ws;  // 8 MB (log2e-scaled fp8)
  size_t off = (size_t)N * D;
  unsigned char* c8 = (unsigned char*)(ws + off);  // 51.5 MB
  off += (size_t)V * D;
  off = (off + 255) & ~(size_t)255;
  float* tgt = (float*)(ws + off);
  off += (size_t)N * 4;
  float* m_part = (float*)(ws + off);
  off += (size_t)NC * N * 4;
  float* s_part = (float*)(ws + off);
  off += (size_t)NC * N * 4;
  double* fin = (double*)(ws + off);
  off += 32 * 2 * sizeof(double);  // total ~61 MB of d_ws

  prep_kernel<<<EB + CB + TGT_BLOCKS, 256, 0, stream>>>(
      e, c, t, (unsigned int*)e8, (unsigned int*)c8, tgt);
  gemm_lse_kernel<<<dim3(NC, N / BM), 256, 0, stream>>>(e8, c8, m_part,
                                                        s_part);
  finalize1_kernel<<<32, 256, 0, stream>>>(m_part, s_part, tgt, t, fin);
  finalize2_kernel<<<1, 64, 0, stream>>>(fin, out);
}